// Round 6
// baseline (320.149 us; speedup 1.0000x reference)
//
#include <hip/hip_runtime.h>
#include <hip/hip_bf16.h>
#include <hip/hip_cooperative_groups.h>

namespace cg = cooperative_groups;

#define BB 8
#define SS 4096
#define DD 1024
#define LL 16
#define SPAD 1032   // summ LDS row stride (halfwords): 16B-aligned b128 A-frag reads

typedef __attribute__((ext_vector_type(8))) short short8;
typedef __attribute__((ext_vector_type(4))) float fl4;

static __device__ __forceinline__ short f2bf(float f) {
    // round-to-nearest-even fp32 -> bf16 (inputs finite, no NaN path needed)
    unsigned u = __float_as_uint(f);
    u += 0x7FFFu + ((u >> 16) & 1u);
    return (short)(u >> 16);
}

// One cooperative kernel, 512 blocks x 256 thr (2 blocks/CU, co-resident).
// Block owns (b, 64-s chunk) for both phases; e lives only in LDS.
//  A: summ->bf16 LDS; per wave one 16(l)x16(s) MFMA score tile (K=1024,
//     compiler-scheduled unroll-8 — R5 showed manual prefetch regresses);
//     exp -> e_lds; per-block Z partial -> Zpart (plain store). blk0 zeroes out.
//  grid.sync()
//  B: coef = w / (sum_ch Zpart)  (4KB L2 read); q[s] = sum_l coef*e_lds;
//     out[b][d] += sum_s q[s]*mem[b][s][d]  (L3-fed re-read, atomic epilogue).
__global__ __launch_bounds__(256) void k_all(const float* __restrict__ mem,
                                             const float* __restrict__ summ,
                                             const float* __restrict__ w,
                                             float* __restrict__ out,
                                             float* __restrict__ Zpart) {
    __shared__ short summ_l[LL * SPAD];   // 33 KB
    __shared__ float e_lds[64 * LL];      // 4 KB
    __shared__ float zp[4][LL];
    __shared__ float zz[16][LL];
    __shared__ float coef[LL];
    __shared__ float qs[64];

    int blk = blockIdx.x;                 // 512 = 8 b x 64 chunks
    int b   = blk >> 6;
    int s0  = (blk & 63) << 6;
    int t    = threadIdx.x;
    int wv   = t >> 6;
    int lane = t & 63;
    int o  = lane & 15;
    int qd = lane >> 4;

    // stage summ as bf16 into LDS (coalesced fl4 reads, b64 LDS writes)
    for (int i = t; i < LL * DD / 4; i += 256) {
        int l = i >> 8, d = (i & 255) * 4;
        fl4 v = *(const fl4*)(summ + l * DD + d);
        short tmp[4];
        tmp[0] = f2bf(v[0]); tmp[1] = f2bf(v[1]);
        tmp[2] = f2bf(v[2]); tmp[3] = f2bf(v[3]);
        *(unsigned long long*)&summ_l[l * SPAD + d] = *(unsigned long long*)tmp;
    }
    if (blk == 0) {                       // zero atomic target before grid.sync
        for (int i = t; i < BB * DD; i += 256) out[i] = 0.f;
    }
    __syncthreads();

    // Phase A: scores for rows s0 + wv*16 .. +15
    // D layout: col(s)=lane&15, row(l)=(lane>>4)*4+reg  [m89-verified]
    const short* arow = summ_l + o * SPAD + qd * 8;
    const float* mrow = mem + ((size_t)b * SS + s0 + wv * 16 + o) * DD + qd * 8;

    fl4 acc = {0.f, 0.f, 0.f, 0.f};
    #pragma unroll 8
    for (int k = 0; k < DD; k += 32) {
        short8 a = *(const short8*)(arow + k);
        fl4 f0 = *(const fl4*)(mrow + k);
        fl4 f1 = *(const fl4*)(mrow + k + 4);
        short8 bb;
        bb[0] = f2bf(f0[0]); bb[1] = f2bf(f0[1]);
        bb[2] = f2bf(f0[2]); bb[3] = f2bf(f0[3]);
        bb[4] = f2bf(f1[0]); bb[5] = f2bf(f1[1]);
        bb[6] = f2bf(f1[2]); bb[7] = f2bf(f1[3]);
        acc = __builtin_amdgcn_mfma_f32_16x16x32_bf16(a, bb, acc, 0, 0, 0);
    }

    const float scale = 0.03125f;  // 1/sqrt(1024)
    fl4 ev;
    #pragma unroll
    for (int r = 0; r < 4; ++r) ev[r] = __expf(acc[r] * scale);
    *(fl4*)&e_lds[(wv * 16 + o) * LL + qd * 4] = ev;   // e[s_local][l]

    // Z partial: sum over the 16 s (o) within each qd group (xor 1,2,4,8 in-group)
    fl4 zs = ev;
    #pragma unroll
    for (int r = 0; r < 4; ++r) {
        float v = zs[r];
        v += __shfl_xor(v, 1, 64);
        v += __shfl_xor(v, 2, 64);
        v += __shfl_xor(v, 4, 64);
        v += __shfl_xor(v, 8, 64);
        zs[r] = v;
    }
    if (o == 0) *(fl4*)&zp[wv][qd * 4] = zs;
    __syncthreads();
    if (t < LL) Zpart[blk * LL + t] = zp[0][t] + zp[1][t] + zp[2][t] + zp[3][t];

    __threadfence();          // make Zpart/out-zero visible device-wide
    cg::this_grid().sync();

    // Phase B: Z reduce (64 chunk-partials of this b), coef, q, ctx
    {
        int l = t & 15, g = t >> 4;      // 16 groups x 4 rows
        float zsum = 0.f;
        #pragma unroll
        for (int j = 0; j < 4; ++j) zsum += Zpart[(b * 64 + g * 4 + j) * LL + l];
        zz[g][l] = zsum;
    }
    __syncthreads();
    if (t < LL) {
        float Zt = 0.f;
        #pragma unroll
        for (int g = 0; g < 16; ++g) Zt += zz[g][t];
        coef[t] = w[t] / Zt;
    }
    __syncthreads();
    if (t < 64) {
        const float* ep = &e_lds[t * LL];
        float qv = 0.f;
        #pragma unroll
        for (int l = 0; l < LL; ++l) qv += coef[l] * ep[l];
        qs[t] = qv;
    }
    __syncthreads();

    const float* mb = mem + ((size_t)b * SS + s0) * DD + t * 4;
    fl4 cacc = {0.f, 0.f, 0.f, 0.f};
    #pragma unroll 8
    for (int i = 0; i < 64; ++i) {
        fl4 m4 = *(const fl4*)(mb + (size_t)i * DD);
        cacc += qs[i] * m4;
    }
    float* op = out + (size_t)b * DD + t * 4;
    atomicAdd(op + 0, cacc[0]);
    atomicAdd(op + 1, cacc[1]);
    atomicAdd(op + 2, cacc[2]);
    atomicAdd(op + 3, cacc[3]);
}

extern "C" void kernel_launch(void* const* d_in, const int* in_sizes, int n_in,
                              void* d_out, int out_size, void* d_ws, size_t ws_size,
                              hipStream_t stream) {
    const float* mem  = (const float*)d_in[0];  // [8,4096,1024] fp32
    const float* summ = (const float*)d_in[1];  // [16,1024] fp32
    const float* w    = (const float*)d_in[2];  // [1,16] fp32
    float* out = (float*)d_out;                 // [8,1024] fp32
    float* Zpart = (float*)d_ws;                // 512*16 floats = 32 KB

    void* args[] = {(void*)&mem, (void*)&summ, (void*)&w, (void*)&out, (void*)&Zpart};
    hipLaunchCooperativeKernel((const void*)k_all, dim3(BB * 64), dim3(256),
                               args, 0, stream);
}

// Round 7
// 221.757 us; speedup vs baseline: 1.4437x; 1.4437x over previous
//
#include <hip/hip_runtime.h>
#include <hip/hip_bf16.h>

#define BB 8
#define SS 4096
#define DD 1024
#define LL 16
#define RSTRIDE 260   // LDS row stride (floats): 256 + 4 pad -> worst 2-way bank alias (free)

typedef __attribute__((ext_vector_type(8))) short short8;
typedef __attribute__((ext_vector_type(4))) float fl4;

static __device__ __forceinline__ short f2bf(float f) {
    // round-to-nearest-even fp32 -> bf16 (inputs finite, no NaN path needed)
    unsigned u = __float_as_uint(f);
    u += 0x7FFFu + ((u >> 16) & 1u);
    return (short)(u >> 16);
}

static __device__ __forceinline__ short8 pack8(fl4 a, fl4 b) {
    short8 r;
    r[0] = f2bf(a[0]); r[1] = f2bf(a[1]); r[2] = f2bf(a[2]); r[3] = f2bf(a[3]);
    r[4] = f2bf(b[0]); r[5] = f2bf(b[1]); r[6] = f2bf(b[2]); r[7] = f2bf(b[3]);
    return r;
}

// Async global->LDS DMA, 16B/lane, dest = wave-uniform base + lane*16 (m104).
static __device__ __forceinline__ void dma16(const float* g, float* l) {
    __builtin_amdgcn_global_load_lds(
        (const __attribute__((address_space(1))) void*)g,
        (__attribute__((address_space(3))) void*)l, 16, 0, 0);
}

// Pass 1: one wave per 16(l)x16(s) tile, 2048 blocks x 64 thr (8 blocks/CU).
// Per k-slice (256 floats/row): 16 global_load_lds_dwordx4 stage 16 rows into
// LDS (16 KB in flight, zero VGPR cost), A-frags read fp32 from L1-resident
// summ + cvt, then ds_read_b128 -> bf16 MFMA. Epilogue: exp -> e[b][s][l],
// per-tile Z partials (plain stores, no atomics). First 128 blocks zero out[].
// D layout: col(s)=lane&15, row(l)=(lane>>4)*4+reg  [m89-verified]
__global__ __launch_bounds__(64) void k_scores(const float* __restrict__ mem,
                                               const float* __restrict__ summ,
                                               float* __restrict__ e,
                                               float* __restrict__ Zpart,
                                               float* __restrict__ out) {
    __shared__ float tl[16 * RSTRIDE];    // 16.6 KB
    int tile = blockIdx.x;                // 2048 = 8 b x 256 tiles
    int b  = tile >> 8;
    int s0 = (tile & 255) << 4;
    int lane = threadIdx.x;
    int o  = lane & 15;                   // s within tile
    int qd = lane >> 4;

    if (tile < 128) out[tile * 64 + lane] = 0.f;   // zero atomic target for k_ctx

    const float* grow = mem + ((size_t)b * SS + s0) * DD + lane * 4;  // DMA src
    const float* arow = summ + o * DD + qd * 8;                        // A src (L1)

    fl4 acc = {0.f, 0.f, 0.f, 0.f};
    for (int ks = 0; ks < 4; ++ks) {
        // drain prior ds_reads before DMA may overwrite the buffer
        asm volatile("s_waitcnt lgkmcnt(0)" ::: "memory");
        const float* gk = grow + ks * 256;
        #pragma unroll
        for (int r = 0; r < 16; ++r)
            dma16(gk + (size_t)r * DD, &tl[r * RSTRIDE]);

        // A fragments for this slice (fp32 -> bf16), overlaps DMA flight time
        short8 afr[8];
        #pragma unroll
        for (int j = 0; j < 8; ++j) {
            fl4 a0 = *(const fl4*)(arow + ks * 256 + j * 32);
            fl4 a1 = *(const fl4*)(arow + ks * 256 + j * 32 + 4);
            afr[j] = pack8(a0, a1);
        }

        asm volatile("s_waitcnt vmcnt(0)" ::: "memory");  // DMA data now in LDS
        #pragma unroll
        for (int j = 0; j < 8; ++j) {
            fl4 f0 = *(const fl4*)&tl[o * RSTRIDE + j * 32 + qd * 8];
            fl4 f1 = *(const fl4*)&tl[o * RSTRIDE + j * 32 + qd * 8 + 4];
            acc = __builtin_amdgcn_mfma_f32_16x16x32_bf16(afr[j], pack8(f0, f1),
                                                          acc, 0, 0, 0);
        }
    }

    const float scale = 0.03125f;  // 1/sqrt(1024)
    fl4 ev;
    #pragma unroll
    for (int r = 0; r < 4; ++r) ev[r] = __expf(acc[r] * scale);
    // e[b][s][l]: s = s0+o, l = qd*4+r -> one fl4 store, 1 KB/wave contiguous
    *(fl4*)&e[((size_t)b * SS + s0 + o) * LL + qd * 4] = ev;

    // Z partial: sum over the 16 s (o) within each qd group (xor 1,2,4,8 in-group)
    fl4 zs = ev;
    #pragma unroll
    for (int r = 0; r < 4; ++r) {
        float v = zs[r];
        v += __shfl_xor(v, 1, 64);
        v += __shfl_xor(v, 2, 64);
        v += __shfl_xor(v, 4, 64);
        v += __shfl_xor(v, 8, 64);
        zs[r] = v;
    }
    if (o == 0) *(fl4*)&Zpart[tile * LL + qd * 4] = zs;   // lanes 0,16,32,48
}

// Pass 2: Z = sum of 256 tile-partials; coef = w/Z; q[s] = sum_l coef*e[b][s][l];
// out[b][d] += sum_{s in 64-chunk} q[s]*mem[b][s][d]  (L3-fed; 16-deep load batches)
__global__ __launch_bounds__(256) void k_ctx(const float* __restrict__ mem,
                                             const float* __restrict__ e,
                                             const float* __restrict__ Zpart,
                                             const float* __restrict__ w,
                                             float* __restrict__ out) {
    int blk = blockIdx.x;            // 512 = 8 b x 64 chunks
    int b  = blk >> 6;
    int s0 = (blk & 63) << 6;
    int t = threadIdx.x;
    __shared__ float zz[16][LL];
    __shared__ float coef[LL];
    __shared__ float qs[64];

    {   // reduce this b's 256 tile-partials (16 KB from L2)
        int l = t & 15, g = t >> 4;
        float zsum = 0.f;
        #pragma unroll
        for (int j = 0; j < 16; ++j)
            zsum += Zpart[(size_t)(b * 256 + g * 16 + j) * LL + l];
        zz[g][l] = zsum;
    }
    __syncthreads();
    if (t < LL) {
        float Zt = 0.f;
        #pragma unroll
        for (int g = 0; g < 16; ++g) Zt += zz[g][t];
        coef[t] = w[t] / Zt;
    }
    __syncthreads();
    if (t < 64) {
        const fl4* ep = (const fl4*)(e + ((size_t)b * SS + s0 + t) * LL);
        fl4 e0 = ep[0], e1 = ep[1], e2 = ep[2], e3 = ep[3];
        float qv = 0.f;
        #pragma unroll
        for (int r = 0; r < 4; ++r)
            qv += coef[r] * e0[r] + coef[4 + r] * e1[r] +
                  coef[8 + r] * e2[r] + coef[12 + r] * e3[r];
        qs[t] = qv;
    }
    __syncthreads();

    const float* mb = mem + ((size_t)b * SS + s0) * DD + t * 4;
    fl4 acc = {0.f, 0.f, 0.f, 0.f};
    for (int g = 0; g < 4; ++g) {        // 4 batches of 16 in-flight fl4 loads
        fl4 v[16];
        #pragma unroll
        for (int j = 0; j < 16; ++j)
            v[j] = *(const fl4*)(mb + (size_t)(g * 16 + j) * DD);
        #pragma unroll
        for (int j = 0; j < 16; ++j)
            acc += qs[g * 16 + j] * v[j];
    }
    float* op = out + (size_t)b * DD + t * 4;
    atomicAdd(op + 0, acc[0]);
    atomicAdd(op + 1, acc[1]);
    atomicAdd(op + 2, acc[2]);
    atomicAdd(op + 3, acc[3]);
}

extern "C" void kernel_launch(void* const* d_in, const int* in_sizes, int n_in,
                              void* d_out, int out_size, void* d_ws, size_t ws_size,
                              hipStream_t stream) {
    const float* mem  = (const float*)d_in[0];  // [8,4096,1024] fp32
    const float* summ = (const float*)d_in[1];  // [16,1024] fp32
    const float* w    = (const float*)d_in[2];  // [1,16] fp32
    float* out = (float*)d_out;                 // [8,1024] fp32

    char* ws = (char*)d_ws;
    float* Zpart = (float*)ws;                  // 2048*16 fl = 128 KB
    float* e     = (float*)(ws + 128 * 1024);   // 2 MB [b][s][l]

    k_scores<<<BB * SS / 16, 64, 0, stream>>>(mem, summ, e, Zpart, out);
    k_ctx<<<BB * 64, 256, 0, stream>>>(mem, e, Zpart, w, out);
}

// Round 8
// 208.578 us; speedup vs baseline: 1.5349x; 1.0632x over previous
//
#include <hip/hip_runtime.h>
#include <hip/hip_bf16.h>

#define BB 8
#define SS 4096
#define DD 1024
#define LL 16
#define ROWF 1028   // LDS row stride in floats (4 KB + 16 B pad -> 2-way bank alias max, free)

typedef __attribute__((ext_vector_type(8))) short short8;
typedef __attribute__((ext_vector_type(4))) float fl4;

static __device__ __forceinline__ short f2bf(float f) {
    // round-to-nearest-even fp32 -> bf16 (inputs finite, no NaN path needed)
    unsigned u = __float_as_uint(f);
    u += 0x7FFFu + ((u >> 16) & 1u);
    return (short)(u >> 16);
}

static __device__ __forceinline__ short8 pack8(fl4 a, fl4 b) {
    short8 r;
    r[0] = f2bf(a[0]); r[1] = f2bf(a[1]); r[2] = f2bf(a[2]); r[3] = f2bf(a[3]);
    r[4] = f2bf(b[0]); r[5] = f2bf(b[1]); r[6] = f2bf(b[2]); r[7] = f2bf(b[3]);
    return r;
}

// Async global->LDS DMA: 16B/lane, per-lane src addr, dest = uniform base + lane*16.
static __device__ __forceinline__ void dma16(const float* g, float* l) {
    __builtin_amdgcn_global_load_lds(
        (const __attribute__((address_space(1))) void*)g,
        (__attribute__((address_space(3))) void*)l, 16, 0, 0);
}

// Single pass over mem. 256 blocks x 256 thr, 1 block/CU (LDS-forced).
// Block owns (b, 128-s segment) = 8 pairs of 16 s. Per pair:
//   B0 barrier -> DMA pair p+1 into other buffer -> s_waitcnt vmcnt(16)
//   (pair p drained) -> B1 -> scores: each wave K=256 slice, 8 x
//   mfma_f32_16x16x32_bf16 (A-frags pre-packed in regs) -> scratch -> B2 ->
//   wave0 combines 4 partials, exp -> e_lds (e never leaves LDS), zacc -> B3 ->
//   PV: per thread ctx[l] += e[s][l]*mem[s][d-quad] (fp32, LDS operands).
// Epilogue: unnormalized ctx partials -> part[blk][l][d] (16 MB total), Zpart.
// D layout: col(s)=lane&15, row(l)=(lane>>4)*4+reg  [m89-verified]
__global__ __launch_bounds__(256) void k_main(const float* __restrict__ mem,
                                              const float* __restrict__ summ,
                                              float* __restrict__ part,
                                              float* __restrict__ Zpart) {
    __shared__ float buf[2][16 * ROWF];   // 131.6 KB
    __shared__ float e_lds[16 * LL];      // 1 KB
    __shared__ float scr[4][256];         // 4 KB

    int blk = blockIdx.x;                 // 256 = 8 b x 32 segments
    int b   = blk >> 5;
    int s_base = (blk & 31) << 7;         // 128 s per block
    int t    = threadIdx.x;
    int wv   = t >> 6;
    int lane = t & 63;
    int o  = lane & 15;
    int qd = lane >> 4;

    // A-frags in registers: wave wv covers K in [wv*256, wv*256+256)
    short8 afr[8];
    {
        const float* arow = summ + o * DD + wv * 256 + qd * 8;
        #pragma unroll
        for (int j = 0; j < 8; ++j) {
            fl4 a0 = *(const fl4*)(arow + j * 32);
            fl4 a1 = *(const fl4*)(arow + j * 32 + 4);
            afr[j] = pack8(a0, a1);
        }
    }

    const float* gseg = mem + ((size_t)b * SS + s_base) * DD;

    // Prologue: DMA pair 0 (wave's share: rows wv*4..wv*4+3, 4 x 1KB chunks each)
    #pragma unroll
    for (int r = 0; r < 4; ++r) {
        int row = wv * 4 + r;
        #pragma unroll
        for (int c = 0; c < 4; ++c)
            dma16(gseg + (size_t)row * DD + c * 256 + lane * 4,
                  &buf[0][row * ROWF + c * 256]);
    }

    fl4 ctx[LL];
    #pragma unroll
    for (int l = 0; l < LL; ++l) ctx[l] = (fl4){0.f, 0.f, 0.f, 0.f};
    fl4 zacc = {0.f, 0.f, 0.f, 0.f};
    const float scale = 0.03125f;  // 1/sqrt(1024)

    for (int p = 0; p < 8; ++p) {
        __syncthreads();              // B0: prior PV done, target buffer free
        if (p < 7) {
            float* nbuf = &buf[(p + 1) & 1][0];
            const float* gp = gseg + (size_t)(p + 1) * 16 * DD;
            #pragma unroll
            for (int r = 0; r < 4; ++r) {
                int row = wv * 4 + r;
                #pragma unroll
                for (int c = 0; c < 4; ++c)
                    dma16(gp + (size_t)row * DD + c * 256 + lane * 4,
                          &nbuf[row * ROWF + c * 256]);
            }
            asm volatile("s_waitcnt vmcnt(16)" ::: "memory");  // pair p drained
        } else {
            asm volatile("s_waitcnt vmcnt(0)" ::: "memory");
        }
        __syncthreads();              // B1: pair p visible to all waves

        const float* bbase = &buf[p & 1][0];
        // scores: this wave's K-slice
        fl4 acc = {0.f, 0.f, 0.f, 0.f};
        const float* brow = bbase + o * ROWF + wv * 256 + qd * 8;
        #pragma unroll
        for (int j = 0; j < 8; ++j) {
            fl4 f0 = *(const fl4*)(brow + j * 32);
            fl4 f1 = *(const fl4*)(brow + j * 32 + 4);
            acc = __builtin_amdgcn_mfma_f32_16x16x32_bf16(afr[j], pack8(f0, f1),
                                                          acc, 0, 0, 0);
        }
        *(fl4*)&scr[wv][lane * 4] = acc;
        __syncthreads();              // B2
        if (wv == 0) {
            fl4 s0 = *(const fl4*)&scr[0][lane * 4];
            fl4 s1 = *(const fl4*)&scr[1][lane * 4];
            fl4 s2 = *(const fl4*)&scr[2][lane * 4];
            fl4 s3 = *(const fl4*)&scr[3][lane * 4];
            fl4 ev;
            #pragma unroll
            for (int r = 0; r < 4; ++r)
                ev[r] = __expf((s0[r] + s1[r] + s2[r] + s3[r]) * scale);
            *(fl4*)&e_lds[o * LL + qd * 4] = ev;   // e[s][l]
            zacc += ev;
        }
        __syncthreads();              // B3: e_lds ready

        // PV: thread t owns d-quad t*4; fp32 operands from LDS
        const float* mrow = bbase + t * 4;
        #pragma unroll 4
        for (int s = 0; s < 16; ++s) {
            fl4 m4 = *(const fl4*)(mrow + s * ROWF);
            const fl4* ee = (const fl4*)&e_lds[s * LL];   // broadcast
            #pragma unroll
            for (int g = 0; g < 4; ++g) {
                fl4 e4 = ee[g];
                ctx[g * 4 + 0] += e4[0] * m4;
                ctx[g * 4 + 1] += e4[1] * m4;
                ctx[g * 4 + 2] += e4[2] * m4;
                ctx[g * 4 + 3] += e4[3] * m4;
            }
        }
    }

    // Epilogue: unnormalized partials + Z partials (no atomics)
    float* pp = part + (size_t)blk * LL * DD + t * 4;
    #pragma unroll
    for (int l = 0; l < LL; ++l) *(fl4*)(pp + (size_t)l * DD) = ctx[l];

    if (wv == 0) {
        #pragma unroll
        for (int r = 0; r < 4; ++r) {   // sum over 16 s (o); xor 1,2,4,8 in-group
            float v = zacc[r];
            v += __shfl_xor(v, 1, 64);
            v += __shfl_xor(v, 2, 64);
            v += __shfl_xor(v, 4, 64);
            v += __shfl_xor(v, 8, 64);
            zacc[r] = v;
        }
        if (o == 0) *(fl4*)&Zpart[blk * LL + qd * 4] = zacc;  // lanes 0,16,32,48
    }
}

// out[b][d] = sum_l (w[l] / sum_seg Zpart) * sum_seg part[b*32+seg][l][d]
__global__ __launch_bounds__(256) void k_out(const float* __restrict__ part,
                                             const float* __restrict__ Zpart,
                                             const float* __restrict__ w,
                                             float* __restrict__ out) {
    int blkid = blockIdx.x;          // 128 = 8 b x 16 d-chunks of 64
    int b  = blkid >> 4;
    int d0 = (blkid & 15) << 6;
    int t = threadIdx.x;
    __shared__ float coef[LL];
    __shared__ float red[4][64];

    if (t < LL) {
        float Z = 0.f;
        #pragma unroll
        for (int s = 0; s < 32; ++s) Z += Zpart[(b * 32 + s) * LL + t];
        coef[t] = w[t] / Z;
    }
    __syncthreads();

    int dd = t & 63, cg = t >> 6;    // 4 groups x 8 segments
    float acc = 0.f;
    for (int seg = cg * 8; seg < cg * 8 + 8; ++seg) {
        const float* pb = part + (size_t)(b * 32 + seg) * LL * DD + d0 + dd;
        #pragma unroll
        for (int l = 0; l < LL; ++l) acc += coef[l] * pb[(size_t)l * DD];
    }
    red[cg][dd] = acc;
    __syncthreads();
    if (t < 64) out[b * DD + d0 + t] = red[0][t] + red[1][t] + red[2][t] + red[3][t];
}

extern "C" void kernel_launch(void* const* d_in, const int* in_sizes, int n_in,
                              void* d_out, int out_size, void* d_ws, size_t ws_size,
                              hipStream_t stream) {
    const float* mem  = (const float*)d_in[0];  // [8,4096,1024] fp32
    const float* summ = (const float*)d_in[1];  // [16,1024] fp32
    const float* w    = (const float*)d_in[2];  // [1,16] fp32
    float* out = (float*)d_out;                 // [8,1024] fp32

    char* ws = (char*)d_ws;
    float* Zpart = (float*)ws;                  // 256*16 fl = 16 KB (pad to 64K)
    float* part  = (float*)(ws + 64 * 1024);    // 256*16*1024 fl = 16 MB

    k_main<<<256, 256, 0, stream>>>(mem, summ, part, Zpart);
    k_out<<<128, 256, 0, stream>>>(part, Zpart, w, out);
}